// Round 2
// baseline (32686.987 us; speedup 1.0000x reference)
//
#include <hip/hip_runtime.h>
#include <math.h>

// ---------------------------------------------------------------------------
// RITS forward: persistent kernel, LDS-resident bf16 weight slices, 512 thr,
// two-level grid barrier. B=256, L=256, D=128, H=256.
// Grid 256 = mt(16 row-tiles of 16) x nt(16 col-slices).
// Per step: P2 (gates_h + x_h/x_c) | P3 (z_h,c_c,out,loss + alpha/gamma(t+1))
//           | P4 (gates + LSTM -> hd)  == 3 grid barriers/step.
// ---------------------------------------------------------------------------

namespace {
constexpr int Bn = 256, Ln = 256, Dn = 128, Hn = 256;
constexpr long LD = (long)Ln * Dn;  // 32768

// ws float offsets
constexpr int OFF_LOSS = 512;                  // sync area = ws[0..511] as uints
constexpr int OFF_DEN  = 576;                  // per-step denom, L floats
constexpr int OFF_HD   = 832;                  // decayed h, (B,H)
constexpr int OFF_XC   = OFF_HD + Bn * Hn;     // 66368: x_c, (B,D)
constexpr int OFF_CC   = OFF_XC + Bn * Dn;     // 99136: c_c, (B,D)
constexpr size_t ZERO_BYTES = (size_t)OFF_XC * 4;  // sync+loss+den+HD zeroed

// dynamic LDS layout (ushorts then floats), total 131744 B
constexpr int SM_WHH  = 0;                 // ushort [64][260]
constexpr int SM_W4   = 64 * 260;          // ushort [32][524]  ([jp][k][2])
constexpr int SM_HIST = SM_W4 + 32 * 524;  // ushort [256][8]
constexpr int SM_WF   = SM_HIST + 2048;    // ushort [128][8]
constexpr int SM_WC   = SM_WF + 1024;      // ushort [256][8]
constexpr int SM_TDH  = SM_WC + 2048;      // ushort [128][16]
constexpr int SM_USHORTS = SM_TDH + 2048;  // 40576 ushorts = 81152 B (16-mult)
constexpr int SMEM_BYTES = 81152 + 4 * 12648;  // + float region = 131744
}  // namespace

__device__ __forceinline__ float bflo(unsigned u) { return __uint_as_float(u << 16); }
__device__ __forceinline__ float bfhi(unsigned u) { return __uint_as_float(u & 0xffff0000u); }
__device__ __forceinline__ float bfu(unsigned short v) { return __uint_as_float(((unsigned)v) << 16); }
__device__ __forceinline__ unsigned short f2bf(float f) {  // RNE
  unsigned u = __float_as_uint(f);
  return (unsigned short)((u + 0x7fffu + ((u >> 16) & 1u)) >> 16);
}

// ---- two-level grid barrier: sub[g]=sync[g*16], master=sync[256], rel[g]=sync[320+g*16]
__device__ __forceinline__ void gridbar(unsigned* sync, unsigned idx) {
  __syncthreads();
  if (threadIdx.x == 0) {
    const unsigned g = blockIdx.x >> 5;  // 8 groups of 32 blocks
    __threadfence();
    unsigned old = __hip_atomic_fetch_add(sync + g * 16, 1u, __ATOMIC_ACQ_REL,
                                          __HIP_MEMORY_SCOPE_AGENT);
    if (old == idx * 32u + 31u) {  // last in group
      unsigned mo = __hip_atomic_fetch_add(sync + 256, 1u, __ATOMIC_ACQ_REL,
                                           __HIP_MEMORY_SCOPE_AGENT);
      if (mo == idx * 8u + 7u) {  // last overall: release everyone
        for (unsigned gg = 0; gg < 8; ++gg)
          __hip_atomic_store(sync + 320 + gg * 16, idx + 1u, __ATOMIC_RELEASE,
                             __HIP_MEMORY_SCOPE_AGENT);
      } else {
        while (__hip_atomic_load(sync + 320 + g * 16, __ATOMIC_ACQUIRE,
                                 __HIP_MEMORY_SCOPE_AGENT) < idx + 1u)
          __builtin_amdgcn_s_sleep(2);
      }
    } else {
      while (__hip_atomic_load(sync + 320 + g * 16, __ATOMIC_ACQUIRE,
                               __HIP_MEMORY_SCOPE_AGENT) < idx + 1u)
        __builtin_amdgcn_s_sleep(2);
    }
    __threadfence();
  }
  __syncthreads();
}

extern __shared__ __align__(16) char smem[];

__global__ __launch_bounds__(512) void rits_main(
    const float* __restrict__ values, const float* __restrict__ masks,
    const float* __restrict__ deltas, const float* __restrict__ evalm,
    const float* __restrict__ td_h_W, const float* __restrict__ td_h_b,
    const float* __restrict__ td_x_w, const float* __restrict__ td_x_b,
    const float* __restrict__ hist_W, const float* __restrict__ hist_b,
    const float* __restrict__ feat_W, const float* __restrict__ feat_b,
    const float* __restrict__ wc_W, const float* __restrict__ wc_b,
    const float* __restrict__ W_ih, const float* __restrict__ W_hh,
    const float* __restrict__ b_ih, const float* __restrict__ b_hh,
    float* __restrict__ ws, float* __restrict__ outp) {
  unsigned short* us = (unsigned short*)smem;
  unsigned short* whh_s = us + SM_WHH;
  unsigned short* w4_s = us + SM_W4;
  unsigned short* hist_s = us + SM_HIST;
  unsigned short* wf_s = us + SM_WF;
  unsigned short* wc_s = us + SM_WC;
  unsigned short* tdh_s = us + SM_TDH;
  float* fbase = (float*)(us + SM_USHORTS);
  float* stg = fbase;          // [4096] A staging
  float* gxm = stg + 4096;     // [4096] gx | m tiles
  float* ptmp = gxm + 4096;    // [2048] partials / reductions
  float* gh_l = ptmp + 2048;   // [16][64] gates_h / pre-acts
  float* c_l = gh_l + 1024;    // [16][16] LSTM cell slice
  float* gn_l = c_l + 256;     // [16][16] gamma_h(t+1) slice
  float* al_l = gn_l + 256;    // [16][8] alpha slice
  float* xh_l = al_l + 128;    // [16][8] x_h slice
  float* den_l = xh_l + 128;   // [256]
  float* b4_l = den_l + 256;   // [64]
  float* hb_l = b4_l + 64;     // [8]
  float* fb_l = hb_l + 8;      // [8]
  float* wcb_l = fb_l + 8;     // [8]
  float* tdb_l = wcb_l + 8;    // [16]
  float* txw_l = tdb_l + 16;   // [128]
  float* txb_l = txw_l + 128;  // [128]

  unsigned* sync = reinterpret_cast<unsigned*>(ws);
  const int tid = threadIdx.x;
  const int bk = blockIdx.x;
  const int nt = bk & 15, mt = bk >> 4;
  const int b0 = mt * 16;
  unsigned bidx = 0;
  float lacc = 0.f;

  // ==================== one-time: load weight slices to LDS =================
  {  // whh_s[c][k] = W_hh[qg*256 + nt*16+jj][k], c=jj*4+qg, stride 260
    int c = tid >> 3, seg = tid & 7;
    int jj = c >> 2, qg = c & 3;
    const float* src = W_hh + (size_t)(qg * 256 + nt * 16 + jj) * 256 + seg * 32;
    unsigned short* dst = whh_s + c * 260 + seg * 32;
    for (int k = 0; k < 32; k += 4) {
      float4 v = *(const float4*)(src + k);
      dst[k] = f2bf(v.x); dst[k + 1] = f2bf(v.y);
      dst[k + 2] = f2bf(v.z); dst[k + 3] = f2bf(v.w);
    }
  }
  {  // w4_s[jp][k][u] = W_ih[(2*q2+u)*256 + nt*16+jj][k], jp=jj*2+q2, stride 524
    int jp = tid >> 4, seg = tid & 15;
    int jj = jp >> 1, q2 = jp & 1;
    const float* s0 = W_ih + (size_t)((2 * q2 + 0) * 256 + nt * 16 + jj) * 256 + seg * 16;
    const float* s1 = W_ih + (size_t)((2 * q2 + 1) * 256 + nt * 16 + jj) * 256 + seg * 16;
    unsigned short* dst = w4_s + jp * 524 + seg * 32;
    for (int k = 0; k < 16; ++k) { dst[2 * k] = f2bf(s0[k]); dst[2 * k + 1] = f2bf(s1[k]); }
  }
  if (tid < 256) {  // hist_s[k][xcl]
    int xcl = tid >> 5, k0 = (tid & 31) * 8;
    const float* src = hist_W + (size_t)(nt * 8 + xcl) * 256 + k0;
    for (int k = 0; k < 8; ++k) hist_s[(k0 + k) * 8 + xcl] = f2bf(src[k]);
  }
  if (tid < 128) {  // wf_s[k][zcl], zero diag
    int zcl = tid >> 4, k0 = (tid & 15) * 8, zg = nt * 8 + zcl;
    const float* src = feat_W + (size_t)zg * 128 + k0;
    for (int k = 0; k < 8; ++k)
      wf_s[(k0 + k) * 8 + zcl] = (k0 + k == zg) ? (unsigned short)0 : f2bf(src[k]);
  }
  if (tid < 256) {  // wc_s[k][acl], K=256
    int acl = tid >> 5, k0 = (tid & 31) * 8;
    const float* src = wc_W + (size_t)(nt * 8 + acl) * 256 + k0;
    for (int k = 0; k < 8; ++k) wc_s[(k0 + k) * 8 + acl] = f2bf(src[k]);
  }
  if (tid < 256) {  // tdh_s[k][hcl], K=128
    int hcl = tid >> 4, k0 = (tid & 15) * 8;
    const float* src = td_h_W + (size_t)(nt * 16 + hcl) * 128 + k0;
    for (int k = 0; k < 8; ++k) tdh_s[(k0 + k) * 16 + hcl] = f2bf(src[k]);
  }
  if (tid < 64) {
    int jj = tid >> 2, qg = tid & 3;
    b4_l[tid] = b_ih[qg * 256 + nt * 16 + jj] + b_hh[qg * 256 + nt * 16 + jj];
  }
  if (tid < 8) { hb_l[tid] = hist_b[nt * 8 + tid]; fb_l[tid] = feat_b[nt * 8 + tid];
                 wcb_l[tid] = wc_b[nt * 8 + tid]; }
  if (tid < 16) tdb_l[tid] = td_h_b[nt * 16 + tid];
  if (tid < 128) { txw_l[tid] = td_x_w[tid]; txb_l[tid] = td_x_b[tid]; }
  if (tid < 256) c_l[tid] = 0.f;
  __syncthreads();

  // ==================== P0: denom(t=bk) + alpha(0) slice =====================
  {
    float s = 0.f;
    for (int i = tid; i < Bn * Dn; i += 512)
      s += evalm[(long)(i >> 7) * LD + (long)bk * Dn + (i & 127)];
    ptmp[tid] = s;
    __syncthreads();
    for (int o = 256; o > 0; o >>= 1) { if (tid < o) ptmp[tid] += ptmp[tid + o]; __syncthreads(); }
    if (tid == 0) ws[OFF_DEN + bk] = ptmp[0] + 1e-5f;
    __syncthreads();
    // gx(0) | m(0) tiles
    for (int i = tid; i < 2048; i += 512) {
      int r = i >> 7, d = i & 127;
      float dv = deltas[(long)(b0 + r) * LD + d];
      gxm[r * 256 + d] = expf(-fmaxf(fmaf(dv, txw_l[d], txb_l[d]), 0.f));
      gxm[r * 256 + 128 + d] = masks[(long)(b0 + r) * LD + d];
    }
    __syncthreads();
    {  // alpha(0) partials: 128 outs x 4 segs, K=256 stride-4
      int o = tid >> 2, seg = tid & 3, r = o >> 3, acl = o & 7;
      const float* G = gxm + r * 256;
      float a = 0.f;
      for (int i = 0; i < 64; ++i) { int k = seg + 4 * i; a = fmaf(G[k], bfu(wc_s[k * 8 + acl]), a); }
      ptmp[tid] = a;
    }
    __syncthreads();
    if (tid < 128) {
      int acl = tid & 7;
      al_l[tid] = ptmp[tid * 4] + ptmp[tid * 4 + 1] + ptmp[tid * 4 + 2] + ptmp[tid * 4 + 3] + wcb_l[acl];
    }
  }
  gridbar(sync, bidx++);
  if (tid < 256) den_l[tid] = ws[OFF_DEN + tid];
  __syncthreads();

  // ============================== time loop ==================================
  for (int t = 0; t < Ln; ++t) {
    // ---------- P2: gates_h (16x64) + x_h/x_c (16x8), K=256 over hd ----------
    {
      const float4* src = (const float4*)(ws + OFF_HD + b0 * Hn);
      float4* dst = (float4*)stg;
      dst[tid] = src[tid]; dst[tid + 512] = src[tid + 512];  // 4096 floats
    }
    __syncthreads();
    {
      int wv = tid >> 6, lane = tid & 63;
      int r0 = wv * 2, r1 = r0 + 1;
      const unsigned short* wp = whh_s + lane * 260;
      const float* A0 = stg + r0 * 256;
      const float* A1 = stg + r1 * 256;
      float acc0 = 0.f, acc1 = 0.f;
#pragma unroll 4
      for (int k = 0; k < 256; k += 4) {
        uint2 w2 = *(const uint2*)(wp + k);
        float w_0 = bflo(w2.x), w_1 = bfhi(w2.x), w_2 = bflo(w2.y), w_3 = bfhi(w2.y);
        float4 a0 = *(const float4*)(A0 + k);
        float4 a1 = *(const float4*)(A1 + k);
        acc0 = fmaf(a0.x, w_0, acc0); acc0 = fmaf(a0.y, w_1, acc0);
        acc0 = fmaf(a0.z, w_2, acc0); acc0 = fmaf(a0.w, w_3, acc0);
        acc1 = fmaf(a1.x, w_0, acc1); acc1 = fmaf(a1.y, w_1, acc1);
        acc1 = fmaf(a1.z, w_2, acc1); acc1 = fmaf(a1.w, w_3, acc1);
      }
      gh_l[r0 * 64 + lane] = acc0;
      gh_l[r1 * 64 + lane] = acc1;
    }
    {  // x_h partials: 128 outs x 4 segs, K=256 stride-4
      int o = tid >> 2, seg = tid & 3, r = o >> 3, xcl = o & 7;
      const float* A = stg + r * 256;
      float a = 0.f;
      for (int i = 0; i < 64; ++i) { int k = seg + 4 * i; a = fmaf(A[k], bfu(hist_s[k * 8 + xcl]), a); }
      ptmp[tid] = a;
    }
    __syncthreads();
    if (tid < 128) {
      int r = tid >> 3, xcl = tid & 7, xg = nt * 8 + xcl, b = b0 + r;
      float xh = ptmp[tid * 4] + ptmp[tid * 4 + 1] + ptmp[tid * 4 + 2] + ptmp[tid * 4 + 3] + hb_l[xcl];
      xh_l[tid] = xh;
      long gi = (long)b * LD + (long)t * Dn + xg;
      float m = masks[gi], v = values[gi];
      ws[OFF_XC + b * Dn + xg] = m * v + (1.f - m) * xh;
    }
    gridbar(sync, bidx++);

    // ---------- P3: z_h -> c_c/out/loss ; gamma_h/gamma_x/alpha(t+1) ----------
    {
      const float4* src = (const float4*)(ws + OFF_XC + b0 * Dn);
      float4* dst = (float4*)stg;
      dst[tid] = src[tid];  // 2048 floats
    }
    if (t + 1 < Ln) {
      for (int i = tid; i < 2048; i += 512) {
        int r = i >> 7, d = i & 127;
        long base = (long)(b0 + r) * LD + (long)(t + 1) * Dn + d;
        float dv = deltas[base];
        stg[2048 + i] = dv;
        gxm[r * 256 + d] = expf(-fmaxf(fmaf(dv, txw_l[d], txb_l[d]), 0.f));
        gxm[r * 256 + 128 + d] = masks[base];
      }
    }
    __syncthreads();
    {  // z partials: 128 outs x 4 segs, K=128 stride-4
      int o = tid >> 2, seg = tid & 3, r = o >> 3, zcl = o & 7;
      const float* A = stg + r * 128;
      float a = 0.f;
      for (int i = 0; i < 32; ++i) { int k = seg + 4 * i; a = fmaf(A[k], bfu(wf_s[k * 8 + zcl]), a); }
      ptmp[tid] = a;
    }
    if (t + 1 < Ln) {
      {  // gamma partials: 256 outs x 2 segs, K=128 stride-2
        int o = tid >> 1, s2 = tid & 1, r = o >> 4, hcl = o & 15;
        const float* Dd = stg + 2048 + r * 128;
        float a = 0.f;
        for (int i = 0; i < 64; ++i) { int k = s2 + 2 * i; a = fmaf(Dd[k], bfu(tdh_s[k * 16 + hcl]), a); }
        ptmp[512 + tid] = a;
      }
      {  // alpha partials: 128 outs x 4 segs, K=256 stride-4
        int o = tid >> 2, seg = tid & 3, r = o >> 3, acl = o & 7;
        const float* G = gxm + r * 256;
        float a = 0.f;
        for (int i = 0; i < 64; ++i) { int k = seg + 4 * i; a = fmaf(G[k], bfu(wc_s[k * 8 + acl]), a); }
        ptmp[1024 + tid] = a;
      }
    }
    __syncthreads();
    if (tid < 128) {
      int r = tid >> 3, zcl = tid & 7, zg = nt * 8 + zcl, b = b0 + r;
      float z = ptmp[tid * 4] + ptmp[tid * 4 + 1] + ptmp[tid * 4 + 2] + ptmp[tid * 4 + 3] + fb_l[zcl];
      float al = al_l[tid], xh = xh_l[tid];
      float ch = al * z + (1.f - al) * xh;
      long gi = (long)b * LD + (long)t * Dn + zg;
      float m = masks[gi], v = values[gi], me = evalm[gi];
      float cc = m * v + (1.f - m) * ch;
      outp[gi] = cc;
      ws[OFF_CC + b * Dn + zg] = cc;
      lacc += fabsf(cc - v) * me / den_l[t];
      if (t + 1 < Ln)
        al_l[tid] = ptmp[1024 + tid * 4] + ptmp[1024 + tid * 4 + 1] +
                    ptmp[1024 + tid * 4 + 2] + ptmp[1024 + tid * 4 + 3] + wcb_l[zcl];
    }
    if (tid >= 128 && tid < 384 && t + 1 < Ln) {
      int o = tid - 128, hcl = o & 15;
      gn_l[o] = expf(-fmaxf(ptmp[512 + o * 2] + ptmp[512 + o * 2 + 1] + tdb_l[hcl], 0.f));
    }
    gridbar(sync, bidx++);

    // ---------- P4: gates = [cc,m]@W_ih + gh + b ; LSTM -> hd ----------
    for (int i = tid; i < 2048; i += 512) {
      int r = i >> 7, d = i & 127;
      stg[r * 256 + d] = ws[OFF_CC + (b0 + r) * Dn + d];
      stg[r * 256 + 128 + d] = masks[(long)(b0 + r) * LD + (long)t * Dn + d];
    }
    __syncthreads();
    {
      int rloc = tid >> 5, jj = tid & 15, q2 = (tid >> 4) & 1, jp = jj * 2 + q2;
      const float* A = stg + rloc * 256;
      const unsigned short* wp = w4_s + jp * 524;
      float g0 = 0.f, g1 = 0.f;
#pragma unroll 4
      for (int k = 0; k < 256; k += 2) {
        uint2 w2 = *(const uint2*)(wp + 2 * k);
        float2 a = *(const float2*)(A + k);
        g0 = fmaf(a.x, bflo(w2.x), g0); g0 = fmaf(a.y, bflo(w2.y), g0);
        g1 = fmaf(a.x, bfhi(w2.x), g1); g1 = fmaf(a.y, bfhi(w2.y), g1);
      }
      int cb = jj * 4 + q2 * 2;
      float p0 = g0 + b4_l[cb] + gh_l[rloc * 64 + cb];
      float p1 = g1 + b4_l[cb + 1] + gh_l[rloc * 64 + cb + 1];
      gh_l[rloc * 64 + cb] = p0;       // own slots: no pre-sync needed
      gh_l[rloc * 64 + cb + 1] = p1;
    }
    __syncthreads();
    if (tid < 256) {
      int b = tid >> 4, j = tid & 15;
      float4 g = *(const float4*)(gh_l + b * 64 + j * 4);
      float ig = 1.f / (1.f + expf(-g.x));
      float fg = 1.f / (1.f + expf(-g.y));
      float gg = tanhf(g.z);
      float og = 1.f / (1.f + expf(-g.w));
      float cnew = fg * c_l[tid] + ig * gg;
      c_l[tid] = cnew;
      if (t + 1 < Ln)
        ws[OFF_HD + (b0 + b) * Hn + nt * 16 + j] = og * tanhf(cnew) * gn_l[tid];
    }
    gridbar(sync, bidx++);
  }

  // ==================== loss reduce + final write ============================
  ptmp[tid] = lacc;
  __syncthreads();
  for (int o = 256; o > 0; o >>= 1) { if (tid < o) ptmp[tid] += ptmp[tid + o]; __syncthreads(); }
  if (tid == 0) atomicAdd(ws + OFF_LOSS, ptmp[0]);
  gridbar(sync, bidx++);
  if (bk == 0 && tid == 0) outp[(long)Bn * LD] = ws[OFF_LOSS];
}

// -------------------- launcher ---------------------------------------------
extern "C" void kernel_launch(void* const* d_in, const int* in_sizes, int n_in,
                              void* d_out, int out_size, void* d_ws,
                              size_t ws_size, hipStream_t stream) {
  const float* values = (const float*)d_in[0];
  const float* masks  = (const float*)d_in[1];
  const float* deltas = (const float*)d_in[2];
  const float* evalm  = (const float*)d_in[3];
  const float* td_h_W = (const float*)d_in[4];
  const float* td_h_b = (const float*)d_in[5];
  const float* td_x_w = (const float*)d_in[6];
  const float* td_x_b = (const float*)d_in[7];
  const float* hist_W = (const float*)d_in[8];
  const float* hist_b = (const float*)d_in[9];
  const float* feat_W = (const float*)d_in[10];
  const float* feat_b = (const float*)d_in[11];
  const float* wc_W   = (const float*)d_in[12];
  const float* wc_b   = (const float*)d_in[13];
  const float* W_ih   = (const float*)d_in[14];
  const float* W_hh   = (const float*)d_in[15];
  const float* b_ih   = (const float*)d_in[16];
  const float* b_hh   = (const float*)d_in[17];
  float* ws = (float*)d_ws;
  float* outp = (float*)d_out;

  hipFuncSetAttribute((const void*)rits_main,
                      hipFuncAttributeMaxDynamicSharedMemorySize, SMEM_BYTES);
  hipMemsetAsync(d_ws, 0, ZERO_BYTES, stream);
  hipLaunchKernelGGL(rits_main, dim3(256), dim3(512), SMEM_BYTES, stream,
                     values, masks, deltas, evalm, td_h_W, td_h_b, td_x_w,
                     td_x_b, hist_W, hist_b, feat_W, feat_b, wc_W, wc_b, W_ih,
                     W_hh, b_ih, b_hh, ws, outp);
}

// Round 3
// 8560.739 us; speedup vs baseline: 3.8182x; 3.8182x over previous
//
#include <hip/hip_runtime.h>
#include <math.h>

// ---------------------------------------------------------------------------
// RITS forward, round 3: ZERO grid barriers.
// Key fact: the scan recurrence (h,c) is independent per batch row; only
// denom(t)=sum(evalm[:,t,:]) couples rows, and it is input-only.
// K1: repack weights to f16-pair layouts + biases + denom.  (one-time)
// K2: 128 persistent blocks x 512 thr; block owns 2 batch rows, runs all 256
//     steps privately (only __syncthreads). Weights stream from L2 each step
//     (~1.25 MB/step, f16 pairs) through v_dot2_f32_f16.
// K3: write loss scalar.
// ---------------------------------------------------------------------------

namespace {
constexpr int Bn = 256, Ln = 256, Dn = 128, Hn = 256;
constexpr long LD = (long)Ln * Dn;  // 32768

// ws byte offsets
constexpr int OFF_LOSS  = 0;
constexpr int OFF_DEN   = 256;      // 256 f32
constexpr int OFF_BIASG = 2048;     // 1024 f32  [jj][q] = b_ih+b_hh
constexpr int OFF_WG    = 8192;     // 262144 dwords: [kp<128][jj<256][8]
                                    //   dwords 0..3 = W_ih pairs q=0..3, 4..7 = W_hh
constexpr int OFF_HISTP = 1056768;  // 16384 dwords [kp<128][d<128]
constexpr int OFF_TDHP  = 1122304;  // 16384 dwords [kp<64][h<256]
constexpr int OFF_WFU   = 1187840;  // 16384 ushort [k<128][d<128] (diag=0)
constexpr int OFF_WCP   = 1220608;  // 16384 dwords [kp<128][d<128]
}  // namespace

typedef _Float16 h2f __attribute__((ext_vector_type(2)));
typedef unsigned int uint32;

__device__ __forceinline__ float fdot2(uint32 a, uint32 b, float c) {
  return __builtin_amdgcn_fdot2(__builtin_bit_cast(h2f, a),
                                __builtin_bit_cast(h2f, b), c, false);
}
__device__ __forceinline__ uint32 packf16(float a, float b) {
  h2f p; p[0] = (_Float16)a; p[1] = (_Float16)b;
  return __builtin_bit_cast(uint32, p);
}
__device__ __forceinline__ unsigned short f16u(float a) {
  _Float16 h = (_Float16)a; return __builtin_bit_cast(unsigned short, h);
}
__device__ __forceinline__ float uf16(unsigned short u) {
  return (float)__builtin_bit_cast(_Float16, u);
}

// ======================= K1: repack + biases + denom ========================
__global__ void rits_prep(const float* __restrict__ td_h_W,
                          const float* __restrict__ hist_W,
                          const float* __restrict__ feat_W,
                          const float* __restrict__ wc_W,
                          const float* __restrict__ W_ih,
                          const float* __restrict__ W_hh,
                          const float* __restrict__ b_ih,
                          const float* __restrict__ b_hh,
                          const float* __restrict__ evalm,
                          char* __restrict__ wsb) {
  const int blk = blockIdx.x, tid = threadIdx.x;
  if (blk < 1248) {
    int idx = blk * 256 + tid;
    if (idx < 262144) {  // wg
      int kp = idx >> 11, rem = idx & 2047, jj = rem >> 3, s8 = rem & 7;
      const float* src = (s8 < 4) ? W_ih : W_hh;
      int q = s8 & 3;
      const float* row = src + (size_t)(q * 256 + jj) * 256 + 2 * kp;
      ((uint32*)(wsb + OFF_WG))[idx] = packf16(row[0], row[1]);
    } else if (idx < 278528) {  // histP
      int i2 = idx - 262144, kp = i2 >> 7, d = i2 & 127;
      ((uint32*)(wsb + OFF_HISTP))[i2] =
          packf16(hist_W[d * 256 + 2 * kp], hist_W[d * 256 + 2 * kp + 1]);
    } else if (idx < 294912) {  // tdhP
      int i2 = idx - 278528, kp = i2 >> 8, h = i2 & 255;
      ((uint32*)(wsb + OFF_TDHP))[i2] =
          packf16(td_h_W[h * 128 + 2 * kp], td_h_W[h * 128 + 2 * kp + 1]);
    } else if (idx < 303104) {  // wfU (plain ushort pairs along d)
      int i2 = idx - 294912, k = i2 >> 6, dp = i2 & 63;
      int d0 = 2 * dp, d1 = d0 + 1;
      float a = (d0 == k) ? 0.f : feat_W[d0 * 128 + k];
      float b = (d1 == k) ? 0.f : feat_W[d1 * 128 + k];
      ((uint32*)(wsb + OFF_WFU))[i2] = packf16(a, b);
    } else if (idx < 319488) {  // wcP
      int i2 = idx - 303104, kp = i2 >> 7, d = i2 & 127;
      ((uint32*)(wsb + OFF_WCP))[i2] =
          packf16(wc_W[d * 256 + 2 * kp], wc_W[d * 256 + 2 * kp + 1]);
    }
  } else if (blk < 1252) {  // biasg
    int i = (blk - 1248) * 256 + tid;
    int jj = i >> 2, q = i & 3;
    ((float*)(wsb + OFF_BIASG))[jj * 4 + q] =
        b_ih[q * 256 + jj] + b_hh[q * 256 + jj];
    if (blk == 1248 && tid == 0) *((float*)(wsb + OFF_LOSS)) = 0.f;
  } else {  // denom per t
    int t = blk - 1252;
    __shared__ float red[256];
    int d = tid & 127, g = tid >> 7;
    float s = 0.f;
    for (int b = g; b < 256; b += 2) s += evalm[(size_t)b * LD + t * 128 + d];
    red[tid] = s;
    __syncthreads();
    for (int o = 128; o > 0; o >>= 1) {
      if (tid < o) red[tid] += red[tid + o];
      __syncthreads();
    }
    if (tid == 0) ((float*)(wsb + OFF_DEN))[t] = red[0] + 1e-5f;
  }
}

// ========================== K2: recurrent blocks ============================
__global__ __launch_bounds__(512) void rits_rec(
    const float* __restrict__ values, const float* __restrict__ masks,
    const float* __restrict__ deltas, const float* __restrict__ evalm,
    const float* __restrict__ td_h_b, const float* __restrict__ td_x_w,
    const float* __restrict__ td_x_b, const float* __restrict__ hist_b,
    const float* __restrict__ feat_b, const float* __restrict__ wc_b,
    char* __restrict__ wsb, float* __restrict__ outp) {
  __shared__ float den_s[256], bg_s[1024], tdhb_s[256];
  __shared__ float txw_s[128], txb_s[128], hb_s[128], fb_s[128], wcb_s[128];
  __shared__ float hf[2][256], cst[2][256];
  __shared__ unsigned short hdU16[128 * 4];  // [kp][2r][slot]
  __shared__ unsigned short cmU16[128 * 4];  // [c_c | m] pairs, same layout
  __shared__ uint32 drP[64 * 2];             // deltas(t) pairs [kp][r]
  __shared__ uint32 gxmP[128 * 2];           // [gamma_x | m] pairs [kp][r]
  __shared__ float xs[2][128], ms[2][128], es[2][128];
  __shared__ float xh[2][128], al[2][128], xcf[2][128];
  __shared__ float zp[2][2][128];
  __shared__ float pg[256 * 8];  // kh1 gate partials / final loss reduce

  const int tid = threadIdx.x;
  const size_t b0 = (size_t)blockIdx.x * 2;
  const uint32* hdU32 = (const uint32*)hdU16;
  const uint32* cmU32 = (const uint32*)cmU16;
  const uint32* wg = (const uint32*)(wsb + OFF_WG);
  const uint32* histP = (const uint32*)(wsb + OFF_HISTP);
  const uint32* tdhP = (const uint32*)(wsb + OFF_TDHP);
  const unsigned short* wfU = (const unsigned short*)(wsb + OFF_WFU);
  const uint32* wcP = (const uint32*)(wsb + OFF_WCP);

  // -------- preload / init --------
  ((float*)hf)[tid] = 0.f;
  ((float*)cst)[tid] = 0.f;
  bg_s[tid] = ((const float*)(wsb + OFF_BIASG))[tid];
  bg_s[tid + 512] = ((const float*)(wsb + OFF_BIASG))[tid + 512];
  if (tid < 256) {
    den_s[tid] = ((const float*)(wsb + OFF_DEN))[tid];
    tdhb_s[tid] = td_h_b[tid];
  } else {
    for (int j = tid - 256; j < 640; j += 256) {
      if (j < 128) txw_s[j] = td_x_w[j];
      else if (j < 256) txb_s[j - 128] = td_x_b[j - 128];
      else if (j < 384) hb_s[j - 256] = hist_b[j - 256];
      else if (j < 512) fb_s[j - 384] = feat_b[j - 384];
      else wcb_s[j - 512] = wc_b[j - 512];
    }
  }
  __syncthreads();

  float lacc = 0.f;
  for (int t = 0; t < Ln; ++t) {
    const size_t base = b0 * LD + (size_t)t * 128;
    // ---- S0: stage inputs; gamma_x & m pairs (input-only) ----
    if (tid < 256) {
      int d = tid & 127, r = tid >> 7;
      size_t gi = base + (size_t)r * LD + d;
      xs[r][d] = values[gi];
      ms[r][d] = masks[gi];
      es[r][d] = evalm[gi];
    } else {
      int i = tid - 256, kp = i & 127, r = i >> 7;
      size_t gb = base + (size_t)r * LD;
      if (kp < 64) {
        float d0v = deltas[gb + 2 * kp], d1v = deltas[gb + 2 * kp + 1];
        drP[kp * 2 + r] = packf16(d0v, d1v);
        float g0 = __expf(-fmaxf(fmaf(d0v, txw_s[2 * kp], txb_s[2 * kp]), 0.f));
        float g1 = __expf(-fmaxf(fmaf(d1v, txw_s[2 * kp + 1], txb_s[2 * kp + 1]), 0.f));
        gxmP[kp * 2 + r] = packf16(g0, g1);
      } else {
        int k2 = kp - 64;
        gxmP[kp * 2 + r] = packf16(masks[gb + 2 * k2], masks[gb + 2 * k2 + 1]);
      }
    }
    __syncthreads();  // A
    // ---- S1: gamma_h(t), hd = h_{t-1} * gamma_h ----
    {
      int h = tid & 255, r = tid >> 8;
      float a = 0.f;
      for (int kp = 0; kp < 64; ++kp) a = fdot2(drP[kp * 2 + r], tdhP[kp * 256 + h], a);
      float gam = __expf(-fmaxf(a + tdhb_s[h], 0.f));
      float hd = hf[r][h] * gam;
      hdU16[(h >> 1) * 4 + 2 * r + (h & 1)] = f16u(hd);
    }
    __syncthreads();  // B
    // ---- S2: x_h & x_c (kh0) | alpha (kh1) ----
    if (tid < 256) {
      int d = tid & 127, r = tid >> 7;
      float a = 0.f;
      for (int kp = 0; kp < 128; ++kp) a = fdot2(hdU32[kp * 2 + r], histP[kp * 128 + d], a);
      float xhv = a + hb_s[d];
      xh[r][d] = xhv;
      float mm = ms[r][d];
      xcf[r][d] = mm * xs[r][d] + (1.f - mm) * xhv;
    } else {
      int i = tid - 256, d = i & 127, r = i >> 7;
      float a = 0.f;
      for (int kp = 0; kp < 128; ++kp) a = fdot2(gxmP[kp * 2 + r], wcP[kp * 128 + d], a);
      al[r][d] = a + wcb_s[d];
    }
    __syncthreads();  // C
    // ---- S3b: z halves ----
    {
      int d = tid & 127, r = (tid >> 7) & 1, kh = tid >> 8;
      float a = 0.f;
      const unsigned short* w = wfU + (kh * 64) * 128 + d;
      const float* A = &xcf[r][kh * 64];
      for (int k = 0; k < 64; ++k) a = fmaf(A[k], uf16(w[k * 128]), a);
      zp[kh][r][d] = a;
    }
    __syncthreads();  // E
    // ---- S3c: c_h, c_c, out, loss, pack [c_c|m] ----
    if (tid < 256) {
      int d = tid & 127, r = tid >> 7;
      float z = zp[0][r][d] + zp[1][r][d] + fb_s[d];
      float a = al[r][d], xhv = xh[r][d];
      float ch = a * z + (1.f - a) * xhv;
      float mm = ms[r][d], xv = xs[r][d];
      float cc = mm * xv + (1.f - mm) * ch;
      outp[base + (size_t)r * LD + d] = cc;
      lacc += (1.f - mm) * fabsf(ch - xv) * es[r][d] / den_s[t];
      cmU16[(d >> 1) * 4 + 2 * r + (d & 1)] = f16u(cc);
      cmU16[(64 + (d >> 1)) * 4 + 2 * r + (d & 1)] = f16u(mm);
    }
    __syncthreads();  // F
    // ---- S4: gates = [c_c,m]@W_ih^T + hd@W_hh^T (k-split by kh) ----
    float acc[2][4] = {};
    {
      int jj = tid & 255, kh = tid >> 8;
      int kp0 = kh * 64;
      const uint32* wp = wg + ((size_t)(kp0 * 256) + jj) * 8;
      for (int kp = 0; kp < 64; ++kp) {
        uint4 wv = ((const uint4*)wp)[0];
        uint4 wh = ((const uint4*)wp)[1];
        wp += 2048;
        uint32 c0 = cmU32[(kp0 + kp) * 2 + 0], c1 = cmU32[(kp0 + kp) * 2 + 1];
        uint32 h0 = hdU32[(kp0 + kp) * 2 + 0], h1 = hdU32[(kp0 + kp) * 2 + 1];
        acc[0][0] = fdot2(c0, wv.x, acc[0][0]); acc[0][1] = fdot2(c0, wv.y, acc[0][1]);
        acc[0][2] = fdot2(c0, wv.z, acc[0][2]); acc[0][3] = fdot2(c0, wv.w, acc[0][3]);
        acc[1][0] = fdot2(c1, wv.x, acc[1][0]); acc[1][1] = fdot2(c1, wv.y, acc[1][1]);
        acc[1][2] = fdot2(c1, wv.z, acc[1][2]); acc[1][3] = fdot2(c1, wv.w, acc[1][3]);
        acc[0][0] = fdot2(h0, wh.x, acc[0][0]); acc[0][1] = fdot2(h0, wh.y, acc[0][1]);
        acc[0][2] = fdot2(h0, wh.z, acc[0][2]); acc[0][3] = fdot2(h0, wh.w, acc[0][3]);
        acc[1][0] = fdot2(h1, wh.x, acc[1][0]); acc[1][1] = fdot2(h1, wh.y, acc[1][1]);
        acc[1][2] = fdot2(h1, wh.z, acc[1][2]); acc[1][3] = fdot2(h1, wh.w, acc[1][3]);
      }
      if (kh) {
        float* p = pg + jj * 8;
        p[0] = acc[0][0]; p[1] = acc[0][1]; p[2] = acc[0][2]; p[3] = acc[0][3];
        p[4] = acc[1][0]; p[5] = acc[1][1]; p[6] = acc[1][2]; p[7] = acc[1][3];
      }
    }
    __syncthreads();  // G
    if (tid < 256) {
      int jj = tid;
      const float* p = pg + jj * 8;
#pragma unroll
      for (int r = 0; r < 2; ++r) {
        float g0 = acc[r][0] + p[r * 4 + 0] + bg_s[jj * 4 + 0];
        float g1 = acc[r][1] + p[r * 4 + 1] + bg_s[jj * 4 + 1];
        float g2 = acc[r][2] + p[r * 4 + 2] + bg_s[jj * 4 + 2];
        float g3 = acc[r][3] + p[r * 4 + 3] + bg_s[jj * 4 + 3];
        float ig = 1.f / (1.f + __expf(-g0));
        float fg = 1.f / (1.f + __expf(-g1));
        float gg = tanhf(g2);
        float og = 1.f / (1.f + __expf(-g3));
        float c = fg * cst[r][jj] + ig * gg;
        cst[r][jj] = c;
        hf[r][jj] = og * tanhf(c);
      }
    }
    __syncthreads();  // H
  }
  // -------- loss reduce --------
  pg[tid] = lacc;
  __syncthreads();
  for (int o = 256; o > 0; o >>= 1) {
    if (tid < o) pg[tid] += pg[tid + o];
    __syncthreads();
  }
  if (tid == 0) atomicAdd((float*)(wsb + OFF_LOSS), pg[0]);
}

// ========================== K3: loss scalar =================================
__global__ void rits_fin(const char* __restrict__ wsb, float* __restrict__ outp) {
  if (threadIdx.x == 0 && blockIdx.x == 0)
    outp[(size_t)Bn * LD] = *((const float*)(wsb + OFF_LOSS));
}

// ============================== launcher ====================================
extern "C" void kernel_launch(void* const* d_in, const int* in_sizes, int n_in,
                              void* d_out, int out_size, void* d_ws,
                              size_t ws_size, hipStream_t stream) {
  const float* values = (const float*)d_in[0];
  const float* masks  = (const float*)d_in[1];
  const float* deltas = (const float*)d_in[2];
  const float* evalm  = (const float*)d_in[3];
  const float* td_h_W = (const float*)d_in[4];
  const float* td_h_b = (const float*)d_in[5];
  const float* td_x_w = (const float*)d_in[6];
  const float* td_x_b = (const float*)d_in[7];
  const float* hist_W = (const float*)d_in[8];
  const float* hist_b = (const float*)d_in[9];
  const float* feat_W = (const float*)d_in[10];
  const float* feat_b = (const float*)d_in[11];
  const float* wc_W   = (const float*)d_in[12];
  const float* wc_b   = (const float*)d_in[13];
  const float* W_ih   = (const float*)d_in[14];
  const float* W_hh   = (const float*)d_in[15];
  const float* b_ih   = (const float*)d_in[16];
  const float* b_hh   = (const float*)d_in[17];
  char* wsb = (char*)d_ws;
  float* outp = (float*)d_out;

  hipLaunchKernelGGL(rits_prep, dim3(1508), dim3(256), 0, stream, td_h_W,
                     hist_W, feat_W, wc_W, W_ih, W_hh, b_ih, b_hh, evalm, wsb);
  hipLaunchKernelGGL(rits_rec, dim3(128), dim3(512), 0, stream, values, masks,
                     deltas, evalm, td_h_b, td_x_w, td_x_b, hist_b, feat_b,
                     wc_b, wsb, outp);
  hipLaunchKernelGGL(rits_fin, dim3(1), dim3(64), 0, stream, wsb, outp);
}

// Round 4
// 3539.993 us; speedup vs baseline: 9.2336x; 2.4183x over previous
//
#include <hip/hip_runtime.h>
#include <math.h>

// ---------------------------------------------------------------------------
// RITS forward, round 4: per-batch-row-independent recurrence (no grid sync),
// 128 blocks x 1024 threads (16 waves/CU), all weight loads 16B-vectorized,
// K-split GEMV phases with LDS reductions. Weights stream from L2 each step.
// B=256, L=256, D=128, H=256.
// ---------------------------------------------------------------------------

namespace {
constexpr int Bn = 256, Ln = 256, Dn = 128, Hn = 256;
constexpr long LD = (long)Ln * Dn;  // 32768

// ws byte offsets
constexpr int OFF_LOSS  = 0;
constexpr int OFF_DEN   = 256;      // 256 f32
constexpr int OFF_BIASG = 2048;     // 1024 f32 [jj][q]
constexpr int OFF_WG    = 8192;     // 262144 dw: [kp<128][jj<256][8]
                                    //   dw 0..3 = W_ih q0..3 pair kp, 4..7 = W_hh
constexpr int OFF_HISTP = 1056768;  // 16384 dw [kp<128][d<128]
constexpr int OFF_TDHP  = 1122304;  // 16384 dw [kp<64][h<256]
constexpr int OFF_WFP   = 1187840;  // 8192 dw  [kp<64][d<128] (diag=0)
constexpr int OFF_WCP   = 1220608;  // 16384 dw [kp<128][d<128]
}  // namespace

typedef _Float16 h2f __attribute__((ext_vector_type(2)));
typedef unsigned int uint32;

__device__ __forceinline__ float fdot2(uint32 a, uint32 b, float c) {
  return __builtin_amdgcn_fdot2(__builtin_bit_cast(h2f, a),
                                __builtin_bit_cast(h2f, b), c, false);
}
__device__ __forceinline__ uint32 packf16(float a, float b) {
  h2f p; p[0] = (_Float16)a; p[1] = (_Float16)b;
  return __builtin_bit_cast(uint32, p);
}
__device__ __forceinline__ unsigned short f16u(float a) {
  _Float16 h = (_Float16)a; return __builtin_bit_cast(unsigned short, h);
}

// ======================= K1: repack + biases + denom ========================
__global__ void rits_prep(const float* __restrict__ td_h_W,
                          const float* __restrict__ hist_W,
                          const float* __restrict__ feat_W,
                          const float* __restrict__ wc_W,
                          const float* __restrict__ W_ih,
                          const float* __restrict__ W_hh,
                          const float* __restrict__ b_ih,
                          const float* __restrict__ b_hh,
                          const float* __restrict__ evalm,
                          char* __restrict__ wsb) {
  const int blk = blockIdx.x, tid = threadIdx.x;
  if (blk < 1248) {
    int idx = blk * 256 + tid;
    if (idx < 262144) {  // wg
      int kp = idx >> 11, rem = idx & 2047, jj = rem >> 3, s8 = rem & 7;
      const float* src = (s8 < 4) ? W_ih : W_hh;
      int q = s8 & 3;
      const float* row = src + (size_t)(q * 256 + jj) * 256 + 2 * kp;
      ((uint32*)(wsb + OFF_WG))[idx] = packf16(row[0], row[1]);
    } else if (idx < 278528) {  // histP
      int i2 = idx - 262144, kp = i2 >> 7, d = i2 & 127;
      ((uint32*)(wsb + OFF_HISTP))[i2] =
          packf16(hist_W[d * 256 + 2 * kp], hist_W[d * 256 + 2 * kp + 1]);
    } else if (idx < 294912) {  // tdhP
      int i2 = idx - 278528, kp = i2 >> 8, h = i2 & 255;
      ((uint32*)(wsb + OFF_TDHP))[i2] =
          packf16(td_h_W[h * 128 + 2 * kp], td_h_W[h * 128 + 2 * kp + 1]);
    } else if (idx < 303104) {  // wfP: [kp<64][d<128], Wf[d][k], diag=0
      int i2 = idx - 294912, kp = i2 >> 7, d = i2 & 127;
      float a = (2 * kp == d) ? 0.f : feat_W[d * 128 + 2 * kp];
      float b = (2 * kp + 1 == d) ? 0.f : feat_W[d * 128 + 2 * kp + 1];
      ((uint32*)(wsb + OFF_WFP))[i2] = packf16(a, b);
    } else if (idx < 319488) {  // wcP
      int i2 = idx - 303104, kp = i2 >> 7, d = i2 & 127;
      ((uint32*)(wsb + OFF_WCP))[i2] =
          packf16(wc_W[d * 256 + 2 * kp], wc_W[d * 256 + 2 * kp + 1]);
    }
  } else if (blk < 1252) {  // biasg
    int i = (blk - 1248) * 256 + tid;
    int jj = i >> 2, q = i & 3;
    ((float*)(wsb + OFF_BIASG))[jj * 4 + q] =
        b_ih[q * 256 + jj] + b_hh[q * 256 + jj];
    if (blk == 1248 && tid == 0) *((float*)(wsb + OFF_LOSS)) = 0.f;
  } else {  // denom per t
    int t = blk - 1252;
    __shared__ float red[256];
    int d = tid & 127, g = tid >> 7;
    float s = 0.f;
    for (int b = g; b < 256; b += 2) s += evalm[(size_t)b * LD + t * 128 + d];
    red[tid] = s;
    __syncthreads();
    for (int o = 128; o > 0; o >>= 1) {
      if (tid < o) red[tid] += red[tid + o];
      __syncthreads();
    }
    if (tid == 0) ((float*)(wsb + OFF_DEN))[t] = red[0] + 1e-5f;
  }
}

// ========================== K2: recurrent blocks ============================
__global__ __launch_bounds__(1024, 4) void rits_rec(
    const float* __restrict__ values, const float* __restrict__ masks,
    const float* __restrict__ deltas, const float* __restrict__ evalm,
    const float* __restrict__ td_h_b, const float* __restrict__ td_x_w,
    const float* __restrict__ td_x_b, const float* __restrict__ hist_b,
    const float* __restrict__ feat_b, const float* __restrict__ wc_b,
    char* __restrict__ wsb, float* __restrict__ outp) {
  __shared__ __align__(16) float scratch[8224];  // shared partial region
  __shared__ float den_s[256], bg_s[1024], tdhb_s[256];
  __shared__ float txw_s[128], txb_s[128], hb_s[128], fb_s[128], wcb_s[128];
  __shared__ float hf[2][256], cst[2][256];
  __shared__ float xs[2][128], ms[2][128], es[2][128];
  __shared__ float xh_s[2][128], al_s[2][128];
  __shared__ __align__(8) unsigned short hdU16[128 * 4];  // h pairs [kp][2r+sl]
  __shared__ __align__(8) unsigned short cmU16[128 * 4];  // [c_c|m] pairs
  __shared__ __align__(8) unsigned short xcU16[64 * 4];   // x_c pairs
  __shared__ uint32 drP[64 * 2];    // deltas pairs [kp][r]
  __shared__ uint32 gxmP[128 * 2];  // [gamma_x|m] pairs [kp][r]

  const int tid = threadIdx.x;
  const size_t b0 = (size_t)blockIdx.x * 2;
  const uint32* hdU32 = (const uint32*)hdU16;
  const uint32* cmU32 = (const uint32*)cmU16;
  const uint32* xcU32 = (const uint32*)xcU16;
  const uint32* wg = (const uint32*)(wsb + OFF_WG);
  const uint4* histP4 = (const uint4*)(wsb + OFF_HISTP);
  const uint4* tdhP4 = (const uint4*)(wsb + OFF_TDHP);
  const uint4* wfP4 = (const uint4*)(wsb + OFF_WFP);
  const uint4* wcP4 = (const uint4*)(wsb + OFF_WCP);

  // -------- preload / init --------
  if (tid < 512) { ((float*)hf)[tid] = 0.f; ((float*)cst)[tid] = 0.f; }
  bg_s[tid] = ((const float*)(wsb + OFF_BIASG))[tid];
  if (tid < 256) {
    den_s[tid] = ((const float*)(wsb + OFF_DEN))[tid];
    tdhb_s[tid] = td_h_b[tid];
  } else if (tid < 384) txw_s[tid - 256] = td_x_w[tid - 256];
  else if (tid < 512) txb_s[tid - 384] = td_x_b[tid - 384];
  else if (tid < 640) hb_s[tid - 512] = hist_b[tid - 512];
  else if (tid < 768) fb_s[tid - 640] = feat_b[tid - 640];
  else if (tid < 896) wcb_s[tid - 768] = wc_b[tid - 768];
  __syncthreads();

  float lacc = 0.f;
  for (int t = 0; t < Ln; ++t) {
    const size_t base = b0 * LD + (size_t)t * 128;
    // ---- A: stage inputs; gamma_x & m pairs ----
    if (tid < 256) {
      int d = tid & 127, r = tid >> 7;
      size_t gi = base + (size_t)r * LD + d;
      xs[r][d] = values[gi];
      ms[r][d] = masks[gi];
      es[r][d] = evalm[gi];
    } else if (tid < 512) {
      int i = tid - 256, kp = i & 127, r = i >> 7;
      size_t gb = base + (size_t)r * LD;
      if (kp < 64) {
        float d0v = deltas[gb + 2 * kp], d1v = deltas[gb + 2 * kp + 1];
        drP[kp * 2 + r] = packf16(d0v, d1v);
        float g0 = __expf(-fmaxf(fmaf(d0v, txw_s[2 * kp], txb_s[2 * kp]), 0.f));
        float g1 = __expf(-fmaxf(fmaf(d1v, txw_s[2 * kp + 1], txb_s[2 * kp + 1]), 0.f));
        gxmP[kp * 2 + r] = packf16(g0, g1);
      } else {
        int k2 = kp - 64;
        gxmP[kp * 2 + r] = packf16(masks[gb + 2 * k2], masks[gb + 2 * k2 + 1]);
      }
    }
    __syncthreads();

    // ---- B: gamma_h partials (256 thr) | alpha partials (512 thr) ----
    if (tid < 256) {  // g=h4 group, r, kq in 0..1 (32 kp each)
      int g = tid & 63, r = (tid >> 6) & 1, kq = tid >> 7;
      float4 a = {0.f, 0.f, 0.f, 0.f};
#pragma unroll 4
      for (int i = 0; i < 32; ++i) {
        int kp = kq * 32 + i;
        uint4 w = tdhP4[kp * 64 + g];
        uint32 dr = drP[kp * 2 + r];
        a.x = fdot2(dr, w.x, a.x); a.y = fdot2(dr, w.y, a.y);
        a.z = fdot2(dr, w.z, a.z); a.w = fdot2(dr, w.w, a.w);
      }
      ((float4*)(scratch + (kq * 2 + r) * 260))[g] = a;
    } else if (tid < 768) {  // alpha: g=d4, r, kq in 0..7 (16 kp each)
      int i0 = tid - 256, g = i0 & 31, r = (i0 >> 5) & 1, kq = i0 >> 6;
      float4 a = {0.f, 0.f, 0.f, 0.f};
#pragma unroll 4
      for (int i = 0; i < 16; ++i) {
        int kp = kq * 16 + i;
        uint4 w = wcP4[kp * 32 + g];
        uint32 gm = gxmP[kp * 2 + r];
        a.x = fdot2(gm, w.x, a.x); a.y = fdot2(gm, w.y, a.y);
        a.z = fdot2(gm, w.z, a.z); a.w = fdot2(gm, w.w, a.w);
      }
      ((float4*)(scratch + 1040 + (kq * 2 + r) * 132))[g] = a;
    }
    __syncthreads();

    // ---- C: reduce gamma_h -> hd pairs ; reduce alpha ----
    if (tid < 512) {
      int h = tid & 255, r = tid >> 8;
      float s = scratch[r * 260 + h] + scratch[(2 + r) * 260 + h] + tdhb_s[h];
      float hd = hf[r][h] * __expf(-fmaxf(s, 0.f));
      hdU16[(h >> 1) * 4 + 2 * r + (h & 1)] = f16u(hd);
    } else if (tid < 768) {
      int i0 = tid - 512, d = i0 & 127, r = i0 >> 7;
      float s = wcb_s[d];
#pragma unroll
      for (int kq = 0; kq < 8; ++kq) s += scratch[1040 + (kq * 2 + r) * 132 + d];
      al_s[r][d] = s;
    }
    __syncthreads();

    // ---- D: x_h partials (512 thr): g=d4, r, kq in 0..7 ----
    if (tid < 512) {
      int g = tid & 31, r = (tid >> 5) & 1, kq = tid >> 6;
      float4 a = {0.f, 0.f, 0.f, 0.f};
#pragma unroll 4
      for (int i = 0; i < 16; ++i) {
        int kp = kq * 16 + i;
        uint4 w = histP4[kp * 32 + g];
        uint32 hd = hdU32[kp * 2 + r];
        a.x = fdot2(hd, w.x, a.x); a.y = fdot2(hd, w.y, a.y);
        a.z = fdot2(hd, w.z, a.z); a.w = fdot2(hd, w.w, a.w);
      }
      ((float4*)(scratch + (kq * 2 + r) * 132))[g] = a;
    }
    __syncthreads();

    // ---- E: x_h, x_c ; pack x_c pairs ----
    if (tid < 256) {
      int d = tid & 127, r = tid >> 7;
      float xh = hb_s[d];
#pragma unroll
      for (int kq = 0; kq < 8; ++kq) xh += scratch[(kq * 2 + r) * 132 + d];
      xh_s[r][d] = xh;
      float mm = ms[r][d];
      float xc = mm * xs[r][d] + (1.f - mm) * xh;
      xcU16[(d >> 1) * 4 + 2 * r + (d & 1)] = f16u(xc);
    }
    __syncthreads();

    // ---- F: z partials (512 thr): g=d4, r, kq in 0..7 (8 kp each) ----
    if (tid < 512) {
      int g = tid & 31, r = (tid >> 5) & 1, kq = tid >> 6;
      float4 a = {0.f, 0.f, 0.f, 0.f};
#pragma unroll 4
      for (int i = 0; i < 8; ++i) {
        int kp = kq * 8 + i;
        uint4 w = wfP4[kp * 32 + g];
        uint32 xc = xcU32[kp * 2 + r];
        a.x = fdot2(xc, w.x, a.x); a.y = fdot2(xc, w.y, a.y);
        a.z = fdot2(xc, w.z, a.z); a.w = fdot2(xc, w.w, a.w);
      }
      ((float4*)(scratch + (kq * 2 + r) * 132))[g] = a;
    }
    __syncthreads();

    // ---- G: c_h, c_c, out, loss, pack [c_c|m] ----
    if (tid < 256) {
      int d = tid & 127, r = tid >> 7;
      float z = fb_s[d];
#pragma unroll
      for (int kq = 0; kq < 8; ++kq) z += scratch[(kq * 2 + r) * 132 + d];
      float a = al_s[r][d], xh = xh_s[r][d];
      float ch = a * z + (1.f - a) * xh;
      float mm = ms[r][d], xv = xs[r][d];
      float cc = mm * xv + (1.f - mm) * ch;
      outp[base + (size_t)r * LD + d] = cc;
      lacc += (1.f - mm) * fabsf(ch - xv) * es[r][d] / den_s[t];
      cmU16[(d >> 1) * 4 + 2 * r + (d & 1)] = f16u(cc);
      cmU16[(64 + (d >> 1)) * 4 + 2 * r + (d & 1)] = f16u(mm);
    }
    __syncthreads();

    // ---- H: gate partials: jj=tid&255, kq=tid>>8 (32 kp each) ----
    {
      int jj = tid & 255, kq = tid >> 8;
      int kp0 = kq * 32;
      const uint4* wp = (const uint4*)(wg + ((size_t)kp0 * 256 + jj) * 8);
      float a00 = 0, a01 = 0, a02 = 0, a03 = 0;
      float a10 = 0, a11 = 0, a12 = 0, a13 = 0;
#pragma unroll 4
      for (int i = 0; i < 32; ++i) {
        int kp = kp0 + i;
        uint4 wv = wp[0];
        uint4 wh = wp[1];
        wp += 512;
        uint32 c0 = cmU32[kp * 2 + 0], c1 = cmU32[kp * 2 + 1];
        uint32 h0 = hdU32[kp * 2 + 0], h1 = hdU32[kp * 2 + 1];
        a00 = fdot2(c0, wv.x, a00); a01 = fdot2(c0, wv.y, a01);
        a02 = fdot2(c0, wv.z, a02); a03 = fdot2(c0, wv.w, a03);
        a10 = fdot2(c1, wv.x, a10); a11 = fdot2(c1, wv.y, a11);
        a12 = fdot2(c1, wv.z, a12); a13 = fdot2(c1, wv.w, a13);
        a00 = fdot2(h0, wh.x, a00); a01 = fdot2(h0, wh.y, a01);
        a02 = fdot2(h0, wh.z, a02); a03 = fdot2(h0, wh.w, a03);
        a10 = fdot2(h1, wh.x, a10); a11 = fdot2(h1, wh.y, a11);
        a12 = fdot2(h1, wh.z, a12); a13 = fdot2(h1, wh.w, a13);
      }
      // pg[slot*257 + jj], slot = kq*8 + r*4 + g  (conflict-free both ways)
      float* pg = scratch;
      pg[(kq * 8 + 0) * 257 + jj] = a00; pg[(kq * 8 + 1) * 257 + jj] = a01;
      pg[(kq * 8 + 2) * 257 + jj] = a02; pg[(kq * 8 + 3) * 257 + jj] = a03;
      pg[(kq * 8 + 4) * 257 + jj] = a10; pg[(kq * 8 + 5) * 257 + jj] = a11;
      pg[(kq * 8 + 6) * 257 + jj] = a12; pg[(kq * 8 + 7) * 257 + jj] = a13;
    }
    __syncthreads();

    // ---- I: reduce gates + LSTM ----
    if (tid < 256) {
      int jj = tid;
      const float* pg = scratch;
#pragma unroll
      for (int r = 0; r < 2; ++r) {
        float g0 = bg_s[jj * 4 + 0], g1 = bg_s[jj * 4 + 1];
        float g2 = bg_s[jj * 4 + 2], g3 = bg_s[jj * 4 + 3];
#pragma unroll
        for (int kq = 0; kq < 4; ++kq) {
          g0 += pg[(kq * 8 + r * 4 + 0) * 257 + jj];
          g1 += pg[(kq * 8 + r * 4 + 1) * 257 + jj];
          g2 += pg[(kq * 8 + r * 4 + 2) * 257 + jj];
          g3 += pg[(kq * 8 + r * 4 + 3) * 257 + jj];
        }
        float ig = 1.f / (1.f + __expf(-g0));
        float fg = 1.f / (1.f + __expf(-g1));
        float gg = tanhf(g2);
        float og = 1.f / (1.f + __expf(-g3));
        float c = fg * cst[r][jj] + ig * gg;
        cst[r][jj] = c;
        hf[r][jj] = og * tanhf(c);
      }
    }
    __syncthreads();
  }

  // -------- loss reduce --------
  scratch[tid] = lacc;
  __syncthreads();
  for (int o = 512; o > 0; o >>= 1) {
    if (tid < o) scratch[tid] += scratch[tid + o];
    __syncthreads();
  }
  if (tid == 0) atomicAdd((float*)(wsb + OFF_LOSS), scratch[0]);
}

// ========================== K3: loss scalar =================================
__global__ void rits_fin(const char* __restrict__ wsb, float* __restrict__ outp) {
  if (threadIdx.x == 0 && blockIdx.x == 0)
    outp[(size_t)Bn * LD] = *((const float*)(wsb + OFF_LOSS));
}

// ============================== launcher ====================================
extern "C" void kernel_launch(void* const* d_in, const int* in_sizes, int n_in,
                              void* d_out, int out_size, void* d_ws,
                              size_t ws_size, hipStream_t stream) {
  const float* values = (const float*)d_in[0];
  const float* masks  = (const float*)d_in[1];
  const float* deltas = (const float*)d_in[2];
  const float* evalm  = (const float*)d_in[3];
  const float* td_h_W = (const float*)d_in[4];
  const float* td_h_b = (const float*)d_in[5];
  const float* td_x_w = (const float*)d_in[6];
  const float* td_x_b = (const float*)d_in[7];
  const float* hist_W = (const float*)d_in[8];
  const float* hist_b = (const float*)d_in[9];
  const float* feat_W = (const float*)d_in[10];
  const float* feat_b = (const float*)d_in[11];
  const float* wc_W   = (const float*)d_in[12];
  const float* wc_b   = (const float*)d_in[13];
  const float* W_ih   = (const float*)d_in[14];
  const float* W_hh   = (const float*)d_in[15];
  const float* b_ih   = (const float*)d_in[16];
  const float* b_hh   = (const float*)d_in[17];
  char* wsb = (char*)d_ws;
  float* outp = (float*)d_out;

  hipLaunchKernelGGL(rits_prep, dim3(1508), dim3(256), 0, stream, td_h_W,
                     hist_W, feat_W, wc_W, W_ih, W_hh, b_ih, b_hh, evalm, wsb);
  hipLaunchKernelGGL(rits_rec, dim3(128), dim3(1024), 0, stream, values, masks,
                     deltas, evalm, td_h_b, td_x_w, td_x_b, hist_b, feat_b,
                     wc_b, wsb, outp);
  hipLaunchKernelGGL(rits_fin, dim3(1), dim3(64), 0, stream, wsb, outp);
}